// Round 1
// baseline (555.139 us; speedup 1.0000x reference)
//
#include <hip/hip_runtime.h>
#include <cstdint>
#include <cstddef>

#define IN_F 768
#define HID  64
#define NNZ1 4915
#define NNZ2 409
#define NNZ3 32
#define BATCH 131072

// ---- workspace layout (bytes) ----
#define OFF_W1D 0u
#define OFF_W2D 196608u          // 768*64*4
#define OFF_W3D 212992u          // +64*64*4
#define OFF_W1F 213248u          // +256 (W3 padded)
#define OFF_W2F 311552u          // +24*4*64*16
#define WS_NEED 319744u

typedef __bf16 bf16x8 __attribute__((ext_vector_type(8)));
typedef float  f32x4  __attribute__((ext_vector_type(4)));
typedef float  f32x8  __attribute__((ext_vector_type(8)));

union FragU { bf16x8 v; uint32_t u[4]; uint4 q; };
union F8U   { float4 f4[2]; f32x8 v8; };

__device__ __forceinline__ uint32_t f2bf1(float f) {
    uint32_t u = __float_as_uint(f);
    return (u + 0x7FFFu + ((u >> 16) & 1u)) >> 16;   // RNE
}
__device__ __forceinline__ uint32_t f2bf2(float lo, float hi) {
    uint32_t a = __float_as_uint(lo);
    uint32_t b = __float_as_uint(hi);
    a = a + 0x7FFFu + ((a >> 16) & 1u);
    b = b + 0x7FFFu + ((b >> 16) & 1u);
    return (a >> 16) | (b & 0xFFFF0000u);
}

// pack 8 fp32 -> bf16x8 via hardware v_cvt_pk_bf16_f32 (RNE, verified: absmax identical)
__device__ __forceinline__ bf16x8 pack8(float4 a, float4 b) {
    F8U u; u.f4[0] = a; u.f4[1] = b;
    return __builtin_convertvector(u.v8, bf16x8);
}

// ---- COO -> dense scatter (duplicates accumulate) ----
__global__ void scatter_coo(const int* __restrict__ idx1, const float* __restrict__ val1,
                            const int* __restrict__ idx2, const float* __restrict__ val2,
                            const int* __restrict__ idx3, const float* __restrict__ val3,
                            float* __restrict__ W1d, float* __restrict__ W2d,
                            float* __restrict__ W3d) {
    int t = blockIdx.x * blockDim.x + threadIdx.x;
    if (t < NNZ1) {
        int r = idx1[t], c = idx1[NNZ1 + t];
        atomicAdd(&W1d[r * HID + c], val1[t]);
    } else if (t < NNZ1 + NNZ2) {
        int i = t - NNZ1;
        int r = idx2[i], c = idx2[NNZ2 + i];
        atomicAdd(&W2d[r * HID + c], val2[i]);
    } else if (t < NNZ1 + NNZ2 + NNZ3) {
        int i = t - NNZ1 - NNZ2;
        int r = idx3[i], c = idx3[NNZ3 + i];
        atomicAdd(&W3d[r * 1 + c], val3[i]);   // OUT==1 -> c==0
    }
}

// ---- dense fp32 -> bf16 MFMA B-fragment layout ----
// W1f uses a PERMUTED k-axis so the mlp kernel's x loads are 64B/lane
// (256B/row) contiguous: within 64-col window w (kstep = 2w+s, s in {0,1}),
//   global_k(quad, j) = 64*w + quad*16 + s*8 + j
// A-side uses the same permutation (lane's 64B slice split into two frags).
// W2f keeps the STANDARD mapping (layer-2 A comes from LDS in standard order):
//   global_k = kstep*32 + quad*8 + j
__global__ void frag_build(const float* __restrict__ W1d, const float* __restrict__ W2d,
                           uint4* __restrict__ W1f, uint4* __restrict__ W2f) {
    int t = blockIdx.x * blockDim.x + threadIdx.x;
    const int n1 = 24 * 4 * 64;
    const int n2 = 2 * 4 * 64;
    if (t < n1) {
        int lane = t & 63;
        int fi = t >> 6;
        int kstep = fi >> 2, nt = fi & 3;
        int m = lane & 15, quad = lane >> 4;
        int kbase = (kstep >> 1) * 64 + quad * 16 + (kstep & 1) * 8;   // permuted
        uint32_t u[4];
#pragma unroll
        for (int jj = 0; jj < 4; ++jj) {
            int k = kbase + jj * 2;
            u[jj] = f2bf2(W1d[k * HID + nt * 16 + m], W1d[(k + 1) * HID + nt * 16 + m]);
        }
        W1f[t] = make_uint4(u[0], u[1], u[2], u[3]);
    } else if (t < n1 + n2) {
        int tt = t - n1;
        int lane = tt & 63;
        int fi = tt >> 6;
        int kstep = fi >> 2, nt = fi & 3;
        int m = lane & 15, quad = lane >> 4;
        uint32_t u[4];
#pragma unroll
        for (int jj = 0; jj < 4; ++jj) {
            int k = kstep * 32 + quad * 8 + jj * 2;                    // standard
            u[jj] = f2bf2(W2d[k * HID + nt * 16 + m], W2d[(k + 1) * HID + nt * 16 + m]);
        }
        W2f[tt] = make_uint4(u[0], u[1], u[2], u[3]);
    }
}

// One layer-1 window. CB = win&1 (compile-time so xw indexing stays in
// registers, rule #20). Issue ORDER inside a window is the whole point:
//   (1) next window's 8 W1f frag loads  (so this window's MFMA wait never
//       has to drain them — they're consumed NEXT window)
//   (2) x prefetch for win+2
//   (3) MFMAs on bqC, which the compiler can start after retiring only
//       loads issued in window win-1 (vmcnt(~16), never vmcnt(0)):
//       the DRAM x prefetch stays in flight across windows.
template<int CB>
__device__ __forceinline__ void window_body(
    int win,
    const float* __restrict__ xr, const uint4* __restrict__ w1p,
    float4 (&xw)[2][4], uint4 (&bqC)[8], uint4 (&bqN)[8], f32x4 (&acc)[4])
{
    if (win + 1 < 12) {
        const uint4* bp = w1p + (size_t)(win + 1) * 8 * 64;
#pragma unroll
        for (int i = 0; i < 8; ++i) bqN[i] = bp[i * 64];
    }
    const float4 x0 = xw[CB][0], x1 = xw[CB][1], x2 = xw[CB][2], x3 = xw[CB][3];
    if (win < 10) {
#pragma unroll
        for (int i = 0; i < 4; ++i)
            xw[CB][i] = *(const float4*)(xr + (win + 2) * 64 + i * 4);
    }
    FragU a0, a1;
    a0.v = pack8(x0, x1);   // s=0: floats 0..7  -> global_k = 64*win + quad*16 + j
    a1.v = pack8(x2, x3);   // s=1: floats 8..15 -> global_k = ... + 8 + j
#pragma unroll
    for (int nt = 0; nt < 4; ++nt) {
        FragU bb; bb.q = bqC[nt];
        acc[nt] = __builtin_amdgcn_mfma_f32_16x16x32_bf16(a0.v, bb.v, acc[nt], 0, 0, 0);
    }
#pragma unroll
    for (int nt = 0; nt < 4; ++nt) {
        FragU bb; bb.q = bqC[4 + nt];
        acc[nt] = __builtin_amdgcn_mfma_f32_16x16x32_bf16(a1.v, bb.v, acc[nt], 0, 0, 0);
    }
}

// ---- fused 3-layer MLP ----
// Block = 256 threads = 4 waves; each wave computes 16 batch rows.
// Layer 1: 12 windows x 64 cols; lane loads 64B contiguous of its row
// (k-permuted frags), x double-buffered 2 windows ahead; W1f fragments
// double-buffered 1 window ahead (bqA/bqB). 8 MFMA/window.
__global__ __launch_bounds__(256) void mlp_fused(
    const float* __restrict__ x,
    const uint4* __restrict__ W1f,
    const uint4* __restrict__ W2f,
    const float* __restrict__ W3d,
    const float* __restrict__ b1,
    const float* __restrict__ b2,
    const float* __restrict__ b3,
    float* __restrict__ out)
{
    __shared__ __align__(16) uint16_t h1s[4][16][72];  // stride 72 u16 = 144B

    const int lane = threadIdx.x & 63;
    const int w    = threadIdx.x >> 6;
    const int m    = lane & 15;
    const int quad = lane >> 4;
    const int rowbase = blockIdx.x * 64 + w * 16;

    f32x4 acc[4] = {{0,0,0,0},{0,0,0,0},{0,0,0,0},{0,0,0,0}};

    // lane's slice of its row: 64B window base = col 64*win + quad*16
    const float* xr = x + (size_t)(rowbase + m) * IN_F + quad * 16;
    const uint4* w1p = W1f + lane;

    // prologue: window-0 B frags + 2 windows of x
    uint4 bqA[8], bqB[8];
#pragma unroll
    for (int i = 0; i < 8; ++i) bqA[i] = w1p[i * 64];

    float4 xw[2][4];
#pragma unroll
    for (int i = 0; i < 4; ++i) {
        xw[0][i] = *(const float4*)(xr + 0 * 64 + i * 4);
        xw[1][i] = *(const float4*)(xr + 1 * 64 + i * 4);
    }

    // 12 windows, software-pipelined; wp loop NOT unrolled (keeps VGPRs and
    // code size bounded; pipelining is explicit via bqA/bqB, so cross-window
    // load hoisting by the compiler isn't needed).
#pragma unroll 1
    for (int wp = 0; wp < 6; ++wp) {
        window_body<0>(2 * wp,     xr, w1p, xw, bqA, bqB, acc);
        window_body<1>(2 * wp + 1, xr, w1p, xw, bqB, bqA, acc);
    }

    // Epilogue 1: h1 = relu(acc + b1) -> LDS as bf16.
    // C layout: col = lane&15 (+16*nt), row = quad*4 + reg.
#pragma unroll
    for (int nt = 0; nt < 4; ++nt) {
        const int col = nt * 16 + m;
        const float bias = b1[col];
#pragma unroll
        for (int r = 0; r < 4; ++r) {
            float h = acc[nt][r] + bias;
            h = h > 0.f ? h : 0.f;
            h1s[w][quad * 4 + r][col] = (uint16_t)f2bf1(h);
        }
    }
    // Same-wave RAW only (each wave reads its own h1s[w]); compiler inserts wait.

    // Layer 2: 2 K-steps x 4 N-tiles (standard frag mapping)
    f32x4 acc2[4] = {{0,0,0,0},{0,0,0,0},{0,0,0,0},{0,0,0,0}};
#pragma unroll
    for (int k2 = 0; k2 < 2; ++k2) {
        FragU a2;
        a2.q = *(const uint4*)&h1s[w][m][k2 * 32 + quad * 8];
#pragma unroll
        for (int nt = 0; nt < 4; ++nt) {
            FragU bb; bb.q = W2f[(k2 * 4 + nt) * 64 + lane];
            acc2[nt] = __builtin_amdgcn_mfma_f32_16x16x32_bf16(a2.v, bb.v, acc2[nt], 0, 0, 0);
        }
    }

    // Epilogue 2 + Layer 3 (fp32)
    float w3v[4];
#pragma unroll
    for (int nt = 0; nt < 4; ++nt) w3v[nt] = W3d[nt * 16 + m];

    float p[4] = {0.f, 0.f, 0.f, 0.f};
#pragma unroll
    for (int nt = 0; nt < 4; ++nt) {
        const float bias = b2[nt * 16 + m];
#pragma unroll
        for (int r = 0; r < 4; ++r) {
            float h = acc2[nt][r] + bias;
            h = h > 0.f ? h : 0.f;
            p[r] += h * w3v[nt];
        }
    }
#pragma unroll
    for (int off = 1; off < 16; off <<= 1) {
#pragma unroll
        for (int r = 0; r < 4; ++r) p[r] += __shfl_xor(p[r], off, 16);
    }
    const float bb3 = b3[0];
    if (m == 0) {
#pragma unroll
        for (int r = 0; r < 4; ++r) out[rowbase + quad * 4 + r] = p[r] + bb3;
    }
}

extern "C" void kernel_launch(void* const* d_in, const int* in_sizes, int n_in,
                              void* d_out, int out_size, void* d_ws, size_t ws_size,
                              hipStream_t stream) {
    const float* x    = (const float*)d_in[0];
    const int*   idx1 = (const int*)  d_in[1];
    const float* val1 = (const float*)d_in[2];
    const float* b1   = (const float*)d_in[3];
    const int*   idx2 = (const int*)  d_in[4];
    const float* val2 = (const float*)d_in[5];
    const float* b2   = (const float*)d_in[6];
    const int*   idx3 = (const int*)  d_in[7];
    const float* val3 = (const float*)d_in[8];
    const float* b3   = (const float*)d_in[9];
    float* out = (float*)d_out;

    char* ws = (char*)d_ws;
    float* W1d = (float*)(ws + OFF_W1D);
    float* W2d = (float*)(ws + OFF_W2D);
    float* W3d = (float*)(ws + OFF_W3D);
    uint4* W1f = (uint4*)(ws + OFF_W1F);
    uint4* W2f = (uint4*)(ws + OFF_W2F);

    // zero the dense weight buffers (ws is poisoned 0xAA before every launch)
    hipMemsetAsync(d_ws, 0, OFF_W1F, stream);

    const int nnz_total = NNZ1 + NNZ2 + NNZ3;
    scatter_coo<<<(nnz_total + 255) / 256, 256, 0, stream>>>(
        idx1, val1, idx2, val2, idx3, val3, W1d, W2d, W3d);

    const int nfrag = 24 * 4 * 64 + 2 * 4 * 64;
    frag_build<<<(nfrag + 255) / 256, 256, 0, stream>>>(W1d, W2d, W1f, W2f);

    mlp_fused<<<BATCH / 64, 256, 0, stream>>>(x, W1f, W2f, W3d, b1, b2, b3, out);
}

// Round 2
// 549.343 us; speedup vs baseline: 1.0106x; 1.0106x over previous
//
#include <hip/hip_runtime.h>
#include <cstdint>
#include <cstddef>

#define IN_F 768
#define HID  64
#define NNZ1 4915
#define NNZ2 409
#define NNZ3 32
#define BATCH 131072

// ---- workspace layout (bytes) ----
#define OFF_W1D 0u
#define OFF_W2D 196608u          // 768*64*4
#define OFF_W3D 212992u          // +64*64*4
#define OFF_W1F 213248u          // +256 (W3 padded)
#define OFF_W2F 311552u          // +24*4*64*16
#define WS_NEED 319744u

typedef __bf16 bf16x8 __attribute__((ext_vector_type(8)));
typedef float  f32x4  __attribute__((ext_vector_type(4)));
typedef float  f32x8  __attribute__((ext_vector_type(8)));

union FragU { bf16x8 v; uint32_t u[4]; uint4 q; };
union F8U   { float4 f4[2]; f32x8 v8; };

__device__ __forceinline__ uint32_t f2bf1(float f) {
    uint32_t u = __float_as_uint(f);
    return (u + 0x7FFFu + ((u >> 16) & 1u)) >> 16;   // RNE
}
__device__ __forceinline__ uint32_t f2bf2(float lo, float hi) {
    uint32_t a = __float_as_uint(lo);
    uint32_t b = __float_as_uint(hi);
    a = a + 0x7FFFu + ((a >> 16) & 1u);
    b = b + 0x7FFFu + ((b >> 16) & 1u);
    return (a >> 16) | (b & 0xFFFF0000u);
}

// pack 8 fp32 -> bf16x8 via hardware v_cvt_pk_bf16_f32 (RNE, verified: absmax identical)
__device__ __forceinline__ bf16x8 pack8(float4 a, float4 b) {
    F8U u; u.f4[0] = a; u.f4[1] = b;
    return __builtin_convertvector(u.v8, bf16x8);
}

// ---- COO -> dense scatter (duplicates accumulate) ----
__global__ void scatter_coo(const int* __restrict__ idx1, const float* __restrict__ val1,
                            const int* __restrict__ idx2, const float* __restrict__ val2,
                            const int* __restrict__ idx3, const float* __restrict__ val3,
                            float* __restrict__ W1d, float* __restrict__ W2d,
                            float* __restrict__ W3d) {
    int t = blockIdx.x * blockDim.x + threadIdx.x;
    if (t < NNZ1) {
        int r = idx1[t], c = idx1[NNZ1 + t];
        atomicAdd(&W1d[r * HID + c], val1[t]);
    } else if (t < NNZ1 + NNZ2) {
        int i = t - NNZ1;
        int r = idx2[i], c = idx2[NNZ2 + i];
        atomicAdd(&W2d[r * HID + c], val2[i]);
    } else if (t < NNZ1 + NNZ2 + NNZ3) {
        int i = t - NNZ1 - NNZ2;
        int r = idx3[i], c = idx3[NNZ3 + i];
        atomicAdd(&W3d[r * 1 + c], val3[i]);   // OUT==1 -> c==0
    }
}

// ---- dense fp32 -> bf16 MFMA B-fragment layout ----
// W1f uses a PERMUTED k-axis so the mlp kernel's x loads are 64B/lane
// (256B/row) contiguous: within 64-col window w (kstep = 2w+s, s in {0,1}),
//   global_k(quad, j) = 64*w + quad*16 + s*8 + j
// A-side uses the same permutation (lane's 64B slice split into two frags).
// W2f keeps the STANDARD mapping (layer-2 A comes from LDS in standard order):
//   global_k = kstep*32 + quad*8 + j
__global__ void frag_build(const float* __restrict__ W1d, const float* __restrict__ W2d,
                           uint4* __restrict__ W1f, uint4* __restrict__ W2f) {
    int t = blockIdx.x * blockDim.x + threadIdx.x;
    const int n1 = 24 * 4 * 64;
    const int n2 = 2 * 4 * 64;
    if (t < n1) {
        int lane = t & 63;
        int fi = t >> 6;
        int kstep = fi >> 2, nt = fi & 3;
        int m = lane & 15, quad = lane >> 4;
        int kbase = (kstep >> 1) * 64 + quad * 16 + (kstep & 1) * 8;   // permuted
        uint32_t u[4];
#pragma unroll
        for (int jj = 0; jj < 4; ++jj) {
            int k = kbase + jj * 2;
            u[jj] = f2bf2(W1d[k * HID + nt * 16 + m], W1d[(k + 1) * HID + nt * 16 + m]);
        }
        W1f[t] = make_uint4(u[0], u[1], u[2], u[3]);
    } else if (t < n1 + n2) {
        int tt = t - n1;
        int lane = tt & 63;
        int fi = tt >> 6;
        int kstep = fi >> 2, nt = fi & 3;
        int m = lane & 15, quad = lane >> 4;
        uint32_t u[4];
#pragma unroll
        for (int jj = 0; jj < 4; ++jj) {
            int k = kstep * 32 + quad * 8 + jj * 2;                    // standard
            u[jj] = f2bf2(W2d[k * HID + nt * 16 + m], W2d[(k + 1) * HID + nt * 16 + m]);
        }
        W2f[tt] = make_uint4(u[0], u[1], u[2], u[3]);
    }
}

// One layer-1 window (local index lw in 0..5; this wave's 6-window half).
// CB = lw&1 (compile-time so xw indexing stays in registers, rule #20).
// Issue order: (1) next window's 8 W1f frag loads (double-buffered bq, so
// this window's MFMA wait never drains them), (2) x prefetch for lw+2,
// (3) MFMAs on bqC — loads stay in flight across windows.
template<int CB>
__device__ __forceinline__ void window_body(
    int lw,
    const float* __restrict__ xr, const uint4* __restrict__ w1p,
    float4 (&xw)[2][4], uint4 (&bqC)[8], uint4 (&bqN)[8], f32x4 (&acc)[4])
{
    if (lw + 1 < 6) {
        const uint4* bp = w1p + (size_t)(lw + 1) * 8 * 64;
#pragma unroll
        for (int i = 0; i < 8; ++i) bqN[i] = bp[i * 64];
    }
    const float4 x0 = xw[CB][0], x1 = xw[CB][1], x2 = xw[CB][2], x3 = xw[CB][3];
    if (lw < 4) {
#pragma unroll
        for (int i = 0; i < 4; ++i)
            xw[CB][i] = *(const float4*)(xr + (lw + 2) * 64 + i * 4);
    }
    FragU a0, a1;
    a0.v = pack8(x0, x1);   // s=0: floats 0..7  -> global_k = 64*gw + quad*16 + j
    a1.v = pack8(x2, x3);   // s=1: floats 8..15 -> global_k = ... + 8 + j
#pragma unroll
    for (int nt = 0; nt < 4; ++nt) {
        FragU bb; bb.q = bqC[nt];
        acc[nt] = __builtin_amdgcn_mfma_f32_16x16x32_bf16(a0.v, bb.v, acc[nt], 0, 0, 0);
    }
#pragma unroll
    for (int nt = 0; nt < 4; ++nt) {
        FragU bb; bb.q = bqC[4 + nt];
        acc[nt] = __builtin_amdgcn_mfma_f32_16x16x32_bf16(a1.v, bb.v, acc[nt], 0, 0, 0);
    }
}

// ---- fused 3-layer MLP, K-split across wave pairs ----
// Block = 256 threads = 4 waves = 2 pairs; pair p = w>>1 owns 16 batch rows;
// half h = w&1 accumulates layer-1 windows 6h..6h+5 (K cols h*384..h*384+383).
// Halves the per-wave serial latency chain and doubles grid parallelism vs
// the 12-window/wave structure; HBM traffic and 256B-chunk coalescing are
// identical. Partials summed through LDS; even wave runs layers 2-3.
__global__ __launch_bounds__(256) void mlp_fused(
    const float* __restrict__ x,
    const uint4* __restrict__ W1f,
    const uint4* __restrict__ W2f,
    const float* __restrict__ W3d,
    const float* __restrict__ b1,
    const float* __restrict__ b2,
    const float* __restrict__ b3,
    float* __restrict__ out)
{
    __shared__ __align__(16) uint16_t h1s[2][16][72];   // stride 72 u16 = 144B
    __shared__ __align__(16) f32x4 pacc[2][4][64];      // [pair][nt][lane]: lane-contig, conflict-free

    const int lane = threadIdx.x & 63;
    const int w    = threadIdx.x >> 6;
    const int p    = w >> 1;
    const int h    = w & 1;
    const int m    = lane & 15;
    const int quad = lane >> 4;
    const int rowbase = blockIdx.x * 32 + p * 16;

    f32x4 acc[4] = {{0,0,0,0},{0,0,0,0},{0,0,0,0},{0,0,0,0}};

    // lane's slice of its row: this half's col base = h*384; window base = lw*64 + quad*16
    const float* xr = x + (size_t)(rowbase + m) * IN_F + quad * 16 + h * 384;
    const uint4* w1p = W1f + (size_t)h * 6 * 8 * 64 + lane;

    // prologue: window-0 B frags + 2 windows of x
    uint4 bqA[8], bqB[8];
#pragma unroll
    for (int i = 0; i < 8; ++i) bqA[i] = w1p[i * 64];

    float4 xw[2][4];
#pragma unroll
    for (int i = 0; i < 4; ++i) {
        xw[0][i] = *(const float4*)(xr + 0 * 64 + i * 4);
        xw[1][i] = *(const float4*)(xr + 1 * 64 + i * 4);
    }

    // 6 windows, software-pipelined; wp loop NOT unrolled (pipelining is
    // explicit via bqA/bqB double-buffer, VGPRs stay bounded).
#pragma unroll 1
    for (int wp = 0; wp < 3; ++wp) {
        window_body<0>(2 * wp,     xr, w1p, xw, bqA, bqB, acc);
        window_body<1>(2 * wp + 1, xr, w1p, xw, bqB, bqA, acc);
    }

    // combine K-halves: odd wave publishes partials, even wave reduces
    if (h == 1) {
#pragma unroll
        for (int nt = 0; nt < 4; ++nt) pacc[p][nt][lane] = acc[nt];
    }
    __syncthreads();
    if (h == 1) return;          // no further barriers below
#pragma unroll
    for (int nt = 0; nt < 4; ++nt) acc[nt] += pacc[p][nt][lane];

    // Epilogue 1: h1 = relu(acc + b1) -> LDS as bf16.
    // C layout: col = lane&15 (+16*nt), row = quad*4 + reg.
#pragma unroll
    for (int nt = 0; nt < 4; ++nt) {
        const int col = nt * 16 + m;
        const float bias = b1[col];
#pragma unroll
        for (int r = 0; r < 4; ++r) {
            float hv = acc[nt][r] + bias;
            hv = hv > 0.f ? hv : 0.f;
            h1s[p][quad * 4 + r][col] = (uint16_t)f2bf1(hv);
        }
    }
    // Same-wave RAW only (each even wave reads its own h1s[p]); compiler inserts wait.

    // Layer 2: 2 K-steps x 4 N-tiles (standard frag mapping)
    f32x4 acc2[4] = {{0,0,0,0},{0,0,0,0},{0,0,0,0},{0,0,0,0}};
#pragma unroll
    for (int k2 = 0; k2 < 2; ++k2) {
        FragU a2;
        a2.q = *(const uint4*)&h1s[p][m][k2 * 32 + quad * 8];
#pragma unroll
        for (int nt = 0; nt < 4; ++nt) {
            FragU bb; bb.q = W2f[(k2 * 4 + nt) * 64 + lane];
            acc2[nt] = __builtin_amdgcn_mfma_f32_16x16x32_bf16(a2.v, bb.v, acc2[nt], 0, 0, 0);
        }
    }

    // Epilogue 2 + Layer 3 (fp32)
    float w3v[4];
#pragma unroll
    for (int nt = 0; nt < 4; ++nt) w3v[nt] = W3d[nt * 16 + m];

    float pr[4] = {0.f, 0.f, 0.f, 0.f};
#pragma unroll
    for (int nt = 0; nt < 4; ++nt) {
        const float bias = b2[nt * 16 + m];
#pragma unroll
        for (int r = 0; r < 4; ++r) {
            float hv = acc2[nt][r] + bias;
            hv = hv > 0.f ? hv : 0.f;
            pr[r] += hv * w3v[nt];
        }
    }
#pragma unroll
    for (int off = 1; off < 16; off <<= 1) {
#pragma unroll
        for (int r = 0; r < 4; ++r) pr[r] += __shfl_xor(pr[r], off, 16);
    }
    const float bb3 = b3[0];
    if (m == 0) {
#pragma unroll
        for (int r = 0; r < 4; ++r) out[rowbase + quad * 4 + r] = pr[r] + bb3;
    }
}

extern "C" void kernel_launch(void* const* d_in, const int* in_sizes, int n_in,
                              void* d_out, int out_size, void* d_ws, size_t ws_size,
                              hipStream_t stream) {
    const float* x    = (const float*)d_in[0];
    const int*   idx1 = (const int*)  d_in[1];
    const float* val1 = (const float*)d_in[2];
    const float* b1   = (const float*)d_in[3];
    const int*   idx2 = (const int*)  d_in[4];
    const float* val2 = (const float*)d_in[5];
    const float* b2   = (const float*)d_in[6];
    const int*   idx3 = (const int*)  d_in[7];
    const float* val3 = (const float*)d_in[8];
    const float* b3   = (const float*)d_in[9];
    float* out = (float*)d_out;

    char* ws = (char*)d_ws;
    float* W1d = (float*)(ws + OFF_W1D);
    float* W2d = (float*)(ws + OFF_W2D);
    float* W3d = (float*)(ws + OFF_W3D);
    uint4* W1f = (uint4*)(ws + OFF_W1F);
    uint4* W2f = (uint4*)(ws + OFF_W2F);

    // zero the dense weight buffers (ws is poisoned 0xAA before every launch)
    hipMemsetAsync(d_ws, 0, OFF_W1F, stream);

    const int nnz_total = NNZ1 + NNZ2 + NNZ3;
    scatter_coo<<<(nnz_total + 255) / 256, 256, 0, stream>>>(
        idx1, val1, idx2, val2, idx3, val3, W1d, W2d, W3d);

    const int nfrag = 24 * 4 * 64 + 2 * 4 * 64;
    frag_build<<<(nfrag + 255) / 256, 256, 0, stream>>>(W1d, W2d, W1f, W2f);

    mlp_fused<<<BATCH / 32, 256, 0, stream>>>(x, W1f, W2f, W3d, b1, b2, b3, out);
}